// Round 8
// baseline (142.755 us; speedup 1.0000x reference)
//
#include <hip/hip_runtime.h>

// Self-attention (SAGAN-style): B=8, C=64, H=W=64 -> N=4096, E=C/8=8.
// Round 8: occupancy + exp-floor. r7 was grid-capped at 16 waves/CU (36%
// occupancy). Now 16 q/block, 2048 blocks, launch_bounds(256,8) -> 8 blocks/CU
// = 32 waves/CU. L1 stays under budget because V loads are masked to lm<9
// (rows 9..15 garbage) and K to quad0: ~1088 B per 84 VALU-cyc chunk = 52 B/cyc
// < 64. Ones-row trick: VT row 8 := 1.0, so GEMM2 computes l = sum(p) in
// C-row 8 (quad2 lanes, reg .x) on the MFMA pipe -- removes the 14-add lacc
// tree + shuffles, and l uses the same truncated p as the numerator (bias
// cancels exactly). Kept from r6/r7: in-register P via permuted key map,
// raw v_exp, masked K loads with one-time zero init, register prefetch,
// fused Wo/residual epilogue, LDS-free qkv.

#define BB   8
#define CC   64
#define NPIX 4096
#define EE   8
#define BN   (BB*NPIX)        // 32768
#define YSZ  (BB*CC*NPIX)     // 2097152
#define LOG2E 1.4426950408889634f

typedef __attribute__((ext_vector_type(8))) short bf16x8;
typedef __attribute__((ext_vector_type(4))) float f32x4;

__device__ __forceinline__ unsigned short f2bf_rne(float x) {
    unsigned u = __float_as_uint(x);
    u += 0x7FFFu + ((u >> 16) & 1u);
    return (unsigned short)(u >> 16);
}
__device__ __forceinline__ unsigned pack_bf_trunc(float a, float b) {
    return (__float_as_uint(a) >> 16) | (__float_as_uint(b) & 0xFFFF0000u);
}

// ---- K1: QKV projection (r7 + ones-row for V) ----
__global__ __launch_bounds__(256) void qkv_kernel(
    const float* __restrict__ x,
    const float* __restrict__ Wk, const float* __restrict__ bk,
    const float* __restrict__ Wq, const float* __restrict__ bq,
    const float* __restrict__ Wv, const float* __restrict__ bv,
    unsigned short* __restrict__ QT, unsigned short* __restrict__ KT,
    unsigned short* __restrict__ VT)
{
    const int proj = blockIdx.y;  // 0=Q, 1=K, 2=V
    const float* W    = (proj == 0) ? Wq : (proj == 1) ? Wk : Wv;
    const float* bias = (proj == 0) ? bq : (proj == 1) ? bk : bv;

    const int bm = blockIdx.x*256 + threadIdx.x;
    const int b  = bm >> 12;
    const int n  = bm & (NPIX-1);
    const float* xb = x + (size_t)b*CC*NPIX + n;

    float xv[CC];
    #pragma unroll
    for (int c = 0; c < CC; ++c) xv[c] = xb[(size_t)c*NPIX];

    float f[EE];
    #pragma unroll
    for (int e = 0; e < EE; ++e) {
        float acc = bias[e];
        #pragma unroll
        for (int c = 0; c < CC; ++c) acc = fmaf(W[e*CC+c], xv[c], acc);
        f[e] = acc;
    }

    if (proj == 0) {
        union { unsigned short s[8]; uint4 v; } t;
        #pragma unroll
        for (int e = 0; e < EE; ++e) t.s[e] = f2bf_rne(f[e] * LOG2E);
        *(uint4*)(QT + (size_t)bm*EE) = t.v;
    } else if (proj == 1) {
        union { unsigned short s[8]; uint4 v; } t;
        #pragma unroll
        for (int e = 0; e < EE; ++e) t.s[e] = f2bf_rne(f[e]);
        *(uint4*)(KT + (size_t)bm*EE) = t.v;
    } else {
        #pragma unroll
        for (int e = 0; e < EE; ++e)
            VT[((size_t)b*16 + e)*NPIX + n] = f2bf_rne(f[e]);
        VT[((size_t)b*16 + 8)*NPIX + n] = 0x3F80;  // ones row -> l via GEMM2
    }
}

// ---- K2: flash attention + fused epilogue. 16 q/block, 8 blocks/CU ----
__global__ __launch_bounds__(256, 8) void attn_fused(
    const unsigned short* __restrict__ QT, const unsigned short* __restrict__ KT,
    const unsigned short* __restrict__ VT,
    const float* __restrict__ x, const float* __restrict__ Wo,
    const float* __restrict__ bo, const float* __restrict__ gamma,
    float* __restrict__ out)
{
    __shared__ float OB[3*256];    // waves 1..3: 64 lanes x f32x4
    __shared__ float VL[16*12];    // normalized v per pixel (stride 12: aligned)
    __shared__ float Wos[CC*9];    // stride 9: conflict-free epilogue reads
    __shared__ float bos[CC];

    const int tid  = threadIdx.x;
    const int wave = tid >> 6, lane = tid & 63;
    const int quad = lane >> 4, lm = lane & 15;
    const int b  = blockIdx.x >> 8;
    const int m0 = (blockIdx.x & 255) * 16;

    for (int i = tid; i < CC*EE; i += 256) Wos[(i>>3)*9 + (i&7)] = Wo[i];
    if (tid < CC) bos[tid] = bo[tid];

    // B1 operand: only quad0 lanes carry real q rows; others stay zero.
    bf16x8 qf = {0,0,0,0,0,0,0,0};
    if (quad == 0)
        qf = *(const bf16x8*)(QT + (size_t)(b*NPIX + m0 + lm)*EE);

    f32x4 oacc = {0.f,0.f,0.f,0.f};
    const f32x4 zc = {0.f,0.f,0.f,0.f};

    const unsigned short* Kb = KT + (size_t)b*NPIX*EE;
    const unsigned short* Vb = VT + (size_t)b*16*NPIX;
    const int n_start = wave*1024;                 // split-K: 1024 keys/wave
    const unsigned short* kl  = Kb + (size_t)(n_start + lm)*EE;
    const unsigned short* vlA = Vb + (size_t)lm*NPIX + n_start + quad*4;

    // prefetch chunk 0. K masked to quad0 (stale regs x qf zero rows = 0);
    // V masked to lm<9 (row 8 = ones for l; rows 9..15 feed discarded C rows).
    bf16x8 kf0n = {0,0,0,0,0,0,0,0}, kf1n = {0,0,0,0,0,0,0,0};
    uint2 vf0n = {0,0}, vf1n = {0,0};
    if (quad == 0) {
        kf0n = *(const bf16x8*)(kl);
        kf1n = *(const bf16x8*)(kl + 16*EE);
    }
    if (lm < 9) {
        vf0n = *(const uint2*)(vlA);
        vf1n = *(const uint2*)(vlA + 16);
    }

    for (int ch = 0; ch < 32; ++ch) {
        bf16x8 kf0 = kf0n, kf1 = kf1n;
        union { bf16x8 v; uint2 h[2]; } vf;
        vf.h[0] = vf0n; vf.h[1] = vf1n;
        kl += 32*EE; vlA += 32;
        if (ch < 31) {                             // prefetch next chunk
            if (quad == 0) {
                kf0n = *(const bf16x8*)(kl);
                kf1n = *(const bf16x8*)(kl + 16*EE);
            }
            if (lm < 9) {
                vf0n = *(const uint2*)(vlA);
                vf1n = *(const uint2*)(vlA + 16);
            }
        }

        // S: C-layout lane (quad,lm) reg r = S[key][query lm];
        // s0: key = 4*quad + r; s1: key = 16 + 4*quad + r.
        f32x4 s0 = __builtin_amdgcn_mfma_f32_16x16x32_bf16(kf0, qf, zc, 0, 0, 0);
        f32x4 s1 = __builtin_amdgcn_mfma_f32_16x16x32_bf16(kf1, qf, zc, 0, 0, 0);

        float p0 = __builtin_amdgcn_exp2f(s0.x), p1 = __builtin_amdgcn_exp2f(s0.y);
        float p2 = __builtin_amdgcn_exp2f(s0.z), p3 = __builtin_amdgcn_exp2f(s0.w);
        float p4 = __builtin_amdgcn_exp2f(s1.x), p5 = __builtin_amdgcn_exp2f(s1.y);
        float p6 = __builtin_amdgcn_exp2f(s1.z), p7 = __builtin_amdgcn_exp2f(s1.w);

        // B2 fragment IS the C-layout regs under the permuted key map
        // (slot k=quad*8+j -> key quad*4+j (j<4) / 16+quad*4+(j-4)),
        // matching the vlA/vlA+16 V load permutation. Verified r6/r7.
        union { unsigned u[4]; bf16x8 v; } pu;
        pu.u[0] = pack_bf_trunc(p0, p1); pu.u[1] = pack_bf_trunc(p2, p3);
        pu.u[2] = pack_bf_trunc(p4, p5); pu.u[3] = pack_bf_trunc(p6, p7);
        oacc = __builtin_amdgcn_mfma_f32_16x16x32_bf16(vf.v, pu.v, oacc, 0, 0, 0);
    }

    // cross-wave combine; l rides along in C-row 8 (quad2 lanes, .x)
    if (wave != 0)
        *(f32x4*)(OB + (size_t)(wave-1)*256 + lane*4) = oacc;
    __syncthreads();
    if (wave == 0) {
        f32x4 o = oacc;
        #pragma unroll
        for (int w = 0; w < 3; ++w)
            o += *(f32x4*)(OB + (size_t)w*256 + lane*4);
        float l   = __shfl(o.x, 32 + lm);          // row 8 = sum of trunc(p)
        float inv = 1.f / l;
        if (quad < 2) {                            // rows e = quad*4+reg in 0..7
            f32x4 st = { o.x*inv, o.y*inv, o.z*inv, o.w*inv };
            *(f32x4*)(VL + lm*12 + quad*4) = st;
        }
    }
    __syncthreads();

    // Fused epilogue: 16 px x 64 ch over 256 threads (4 ch each).
    const float g  = gamma[0];
    const int   px = tid & 15;
    const int   cg = tid >> 4;                     // 0..15
    const size_t base = (size_t)b*CC*NPIX + (m0 + px);
    float v[EE];
    #pragma unroll
    for (int e = 0; e < EE; ++e) v[e] = VL[px*12 + e];
    #pragma unroll
    for (int i = 0; i < 4; ++i) {
        const int c = cg*4 + i;
        float o = bos[c];
        #pragma unroll
        for (int e = 0; e < EE; ++e) o += Wos[c*9 + e] * v[e];
        out[(size_t)YSZ + base + (size_t)c*NPIX] = o;
        out[base + (size_t)c*NPIX] = g*o + x[base + (size_t)c*NPIX];
    }
    if (blockIdx.x == 0 && tid == 0) out[2*(size_t)YSZ] = g;  // gamma passthrough
}

extern "C" void kernel_launch(void* const* d_in, const int* in_sizes, int n_in,
                              void* d_out, int out_size, void* d_ws, size_t ws_size,
                              hipStream_t stream) {
    const float* x     = (const float*)d_in[0];
    const float* Wk    = (const float*)d_in[1];
    const float* bk    = (const float*)d_in[2];
    const float* Wq    = (const float*)d_in[3];
    const float* bq    = (const float*)d_in[4];
    const float* Wv    = (const float*)d_in[5];
    const float* bv    = (const float*)d_in[6];
    const float* Wo    = (const float*)d_in[7];
    const float* bo    = (const float*)d_in[8];
    const float* gamma = (const float*)d_in[9];
    float* out = (float*)d_out;

    // ws: QT(512KB) | KT(512KB) | VT(1MB bf16 [b][16][N]; row 8 = ones,
    // rows 9..15 poison -> only discarded C rows) = 2MB
    unsigned short* QT = (unsigned short*)d_ws;
    unsigned short* KT = QT + (size_t)BN*EE;
    unsigned short* VT = KT + (size_t)BN*EE;

    qkv_kernel<<<dim3(BN/256, 3), 256, 0, stream>>>(x, Wk, bk, Wq, bq, Wv, bv, QT, KT, VT);
    attn_fused<<<BB*256, 256, 0, stream>>>(QT, KT, VT, x, Wo, bo, gamma, out);
}

// Round 9
// 119.706 us; speedup vs baseline: 1.1925x; 1.1925x over previous
//
#include <hip/hip_runtime.h>

// Self-attention (SAGAN-style): B=8, C=64, H=W=64 -> N=4096, E=C/8=8.
// Round 9: kill the L1 set-aliasing on V. r6-r8's V loads walked 9-16 rows
// at 8KB stride -> every row maps to the SAME L1 set (32KB cache), thrashing
// a ~4-way set across 32 waves/CU; all waves sat 97% stalled (VALUBusy 28%).
// Fix: panelized V layout VT[b][panel=n/32][row e(16)][32 keys], 1KB panels.
// Row = 64B; quad q's fragment shorts at offset q*8: [4q..4q+3, 16+4q..+3]
// -- exactly the permuted key map GEMM2 already uses (verified r6-r8). The
// V fragment is now ONE 16B load, and a wave's V reads span one contiguous
// 1KB panel -> consecutive L1 sets, no aliasing. Ones-row (e=8) lives in the
// panel, so l = sum(p) still rides C-row 8 on the MFMA pipe.
// Kept: masked K loads (quad0, 256B contiguous), in-register P, raw v_exp,
// register prefetch, fused Wo/residual epilogue, launch_bounds(256,8).
// Note: total-minus-attn ~83us is fixed harness overhead (constant across
// rounds 1-8 regardless of kernel count); attn is the only lever.

#define BB   8
#define CC   64
#define NPIX 4096
#define EE   8
#define BN   (BB*NPIX)        // 32768
#define YSZ  (BB*CC*NPIX)     // 2097152
#define LOG2E 1.4426950408889634f

typedef __attribute__((ext_vector_type(8))) short bf16x8;
typedef __attribute__((ext_vector_type(4))) float f32x4;

__device__ __forceinline__ unsigned short f2bf_rne(float x) {
    unsigned u = __float_as_uint(x);
    u += 0x7FFFu + ((u >> 16) & 1u);
    return (unsigned short)(u >> 16);
}
__device__ __forceinline__ unsigned pack_bf_trunc(float a, float b) {
    return (__float_as_uint(a) >> 16) | (__float_as_uint(b) & 0xFFFF0000u);
}

// ---- K1: QKV projection; V written in panel layout ----
__global__ __launch_bounds__(256) void qkv_kernel(
    const float* __restrict__ x,
    const float* __restrict__ Wk, const float* __restrict__ bk,
    const float* __restrict__ Wq, const float* __restrict__ bq,
    const float* __restrict__ Wv, const float* __restrict__ bv,
    unsigned short* __restrict__ QT, unsigned short* __restrict__ KT,
    unsigned short* __restrict__ VT)
{
    const int proj = blockIdx.y;  // 0=Q, 1=K, 2=V
    const float* W    = (proj == 0) ? Wq : (proj == 1) ? Wk : Wv;
    const float* bias = (proj == 0) ? bq : (proj == 1) ? bk : bv;

    const int bm = blockIdx.x*256 + threadIdx.x;
    const int b  = bm >> 12;
    const int n  = bm & (NPIX-1);
    const float* xb = x + (size_t)b*CC*NPIX + n;

    float xv[CC];
    #pragma unroll
    for (int c = 0; c < CC; ++c) xv[c] = xb[(size_t)c*NPIX];

    float f[EE];
    #pragma unroll
    for (int e = 0; e < EE; ++e) {
        float acc = bias[e];
        #pragma unroll
        for (int c = 0; c < CC; ++c) acc = fmaf(W[e*CC+c], xv[c], acc);
        f[e] = acc;
    }

    if (proj == 0) {
        union { unsigned short s[8]; uint4 v; } t;
        #pragma unroll
        for (int e = 0; e < EE; ++e) t.s[e] = f2bf_rne(f[e] * LOG2E);
        *(uint4*)(QT + (size_t)bm*EE) = t.v;
    } else if (proj == 1) {
        union { unsigned short s[8]; uint4 v; } t;
        #pragma unroll
        for (int e = 0; e < EE; ++e) t.s[e] = f2bf_rne(f[e]);
        *(uint4*)(KT + (size_t)bm*EE) = t.v;
    } else {
        // panel p = n>>5; within-row short offset for key c = n&31:
        // quad q(c) block of 8 shorts: [0..3]=keys 4q..4q+3, [4..7]=keys 16+4q..+3
        const int p   = n >> 5;
        const int c   = n & 31;
        const int off = ((c & 15) >> 2)*8 + ((c >> 4) << 2) + (c & 3);
        unsigned short* vp = VT + ((size_t)(b*128 + p)*16)*32 + off;
        #pragma unroll
        for (int e = 0; e < EE; ++e) vp[e*32] = f2bf_rne(f[e]);
        vp[8*32] = 0x3F80;                         // ones row -> l via GEMM2
    }
}

// ---- K2: flash attention + fused epilogue. 16 q/block, 8 blocks/CU ----
__global__ __launch_bounds__(256, 8) void attn_fused(
    const unsigned short* __restrict__ QT, const unsigned short* __restrict__ KT,
    const unsigned short* __restrict__ VT,
    const float* __restrict__ x, const float* __restrict__ Wo,
    const float* __restrict__ bo, const float* __restrict__ gamma,
    float* __restrict__ out)
{
    __shared__ float OB[3*256];    // waves 1..3: 64 lanes x f32x4
    __shared__ float VL[16*12];    // normalized v per pixel
    __shared__ float Wos[CC*9];    // stride 9: conflict-free epilogue reads
    __shared__ float bos[CC];

    const int tid  = threadIdx.x;
    const int wave = tid >> 6, lane = tid & 63;
    const int quad = lane >> 4, lm = lane & 15;
    const int b  = blockIdx.x >> 8;
    const int m0 = (blockIdx.x & 255) * 16;

    for (int i = tid; i < CC*EE; i += 256) Wos[(i>>3)*9 + (i&7)] = Wo[i];
    if (tid < CC) bos[tid] = bo[tid];

    // B1 operand: only quad0 lanes carry real q rows; others stay zero.
    bf16x8 qf = {0,0,0,0,0,0,0,0};
    if (quad == 0)
        qf = *(const bf16x8*)(QT + (size_t)(b*NPIX + m0 + lm)*EE);

    f32x4 oacc = {0.f,0.f,0.f,0.f};
    const f32x4 zc = {0.f,0.f,0.f,0.f};

    const unsigned short* Kb = KT + (size_t)b*NPIX*EE;
    const int n_start = wave*1024;                 // split-K: 1024 keys/wave
    const unsigned short* kl = Kb + (size_t)(n_start + lm)*EE;
    // V panel pointer: row lm, quad block; advances one 512-short panel/chunk
    const unsigned short* vl = VT + ((size_t)(b*128 + (n_start >> 5))*16 + lm)*32
                                  + quad*8;

    // prefetch chunk 0. K masked to quad0 (stale regs x qf zero rows = 0);
    // V masked to lm<9 (row 8 = ones; rows 9..15 feed discarded C rows).
    bf16x8 kf0n = {0,0,0,0,0,0,0,0}, kf1n = {0,0,0,0,0,0,0,0};
    bf16x8 vfn  = {0,0,0,0,0,0,0,0};
    if (quad == 0) {
        kf0n = *(const bf16x8*)(kl);
        kf1n = *(const bf16x8*)(kl + 16*EE);
    }
    if (lm < 9) vfn = *(const bf16x8*)(vl);

    for (int ch = 0; ch < 32; ++ch) {
        bf16x8 kf0 = kf0n, kf1 = kf1n, vf = vfn;
        kl += 32*EE; vl += 512;
        if (ch < 31) {                             // prefetch next chunk
            if (quad == 0) {
                kf0n = *(const bf16x8*)(kl);
                kf1n = *(const bf16x8*)(kl + 16*EE);
            }
            if (lm < 9) vfn = *(const bf16x8*)(vl);
        }

        // S: C-layout lane (quad,lm) reg r = S[key][query lm];
        // s0: key = 4*quad + r; s1: key = 16 + 4*quad + r.
        f32x4 s0 = __builtin_amdgcn_mfma_f32_16x16x32_bf16(kf0, qf, zc, 0, 0, 0);
        f32x4 s1 = __builtin_amdgcn_mfma_f32_16x16x32_bf16(kf1, qf, zc, 0, 0, 0);

        float p0 = __builtin_amdgcn_exp2f(s0.x), p1 = __builtin_amdgcn_exp2f(s0.y);
        float p2 = __builtin_amdgcn_exp2f(s0.z), p3 = __builtin_amdgcn_exp2f(s0.w);
        float p4 = __builtin_amdgcn_exp2f(s1.x), p5 = __builtin_amdgcn_exp2f(s1.y);
        float p6 = __builtin_amdgcn_exp2f(s1.z), p7 = __builtin_amdgcn_exp2f(s1.w);

        // B2 fragment IS the C-layout regs under the permuted key map
        // (slot k=quad*8+j -> key quad*4+j (j<4) / 16+quad*4+(j-4)),
        // matching the V panel row layout. Verified r6-r8.
        union { unsigned u[4]; bf16x8 v; } pu;
        pu.u[0] = pack_bf_trunc(p0, p1); pu.u[1] = pack_bf_trunc(p2, p3);
        pu.u[2] = pack_bf_trunc(p4, p5); pu.u[3] = pack_bf_trunc(p6, p7);
        oacc = __builtin_amdgcn_mfma_f32_16x16x32_bf16(vf, pu.v, oacc, 0, 0, 0);
    }

    // cross-wave combine; l rides along in C-row 8 (quad2 lanes, reg .x)
    if (wave != 0)
        *(f32x4*)(OB + (size_t)(wave-1)*256 + lane*4) = oacc;
    __syncthreads();
    if (wave == 0) {
        f32x4 o = oacc;
        #pragma unroll
        for (int w = 0; w < 3; ++w)
            o += *(f32x4*)(OB + (size_t)w*256 + lane*4);
        float l   = __shfl(o.x, 32 + lm);          // row 8 = sum of trunc(p)
        float inv = 1.f / l;
        if (quad < 2) {                            // rows e = quad*4+reg in 0..7
            f32x4 st = { o.x*inv, o.y*inv, o.z*inv, o.w*inv };
            *(f32x4*)(VL + lm*12 + quad*4) = st;
        }
    }
    __syncthreads();

    // Fused epilogue: 16 px x 64 ch over 256 threads (4 ch each).
    const float g  = gamma[0];
    const int   px = tid & 15;
    const int   cg = tid >> 4;                     // 0..15
    const size_t base = (size_t)b*CC*NPIX + (m0 + px);
    float v[EE];
    #pragma unroll
    for (int e = 0; e < EE; ++e) v[e] = VL[px*12 + e];
    #pragma unroll
    for (int i = 0; i < 4; ++i) {
        const int c = cg*4 + i;
        float o = bos[c];
        #pragma unroll
        for (int e = 0; e < EE; ++e) o += Wos[c*9 + e] * v[e];
        out[(size_t)YSZ + base + (size_t)c*NPIX] = o;
        out[base + (size_t)c*NPIX] = g*o + x[base + (size_t)c*NPIX];
    }
    if (blockIdx.x == 0 && tid == 0) out[2*(size_t)YSZ] = g;  // gamma passthrough
}

extern "C" void kernel_launch(void* const* d_in, const int* in_sizes, int n_in,
                              void* d_out, int out_size, void* d_ws, size_t ws_size,
                              hipStream_t stream) {
    const float* x     = (const float*)d_in[0];
    const float* Wk    = (const float*)d_in[1];
    const float* bk    = (const float*)d_in[2];
    const float* Wq    = (const float*)d_in[3];
    const float* bq    = (const float*)d_in[4];
    const float* Wv    = (const float*)d_in[5];
    const float* bv    = (const float*)d_in[6];
    const float* Wo    = (const float*)d_in[7];
    const float* bo    = (const float*)d_in[8];
    const float* gamma = (const float*)d_in[9];
    float* out = (float*)d_out;

    // ws: QT(512KB) | KT(512KB) | VT(1MB bf16, panelized [b][128][16][32];
    // row 8 = ones, rows 9..15 poison -> only discarded C rows) = 2MB
    unsigned short* QT = (unsigned short*)d_ws;
    unsigned short* KT = QT + (size_t)BN*EE;
    unsigned short* VT = KT + (size_t)BN*EE;

    qkv_kernel<<<dim3(BN/256, 3), 256, 0, stream>>>(x, Wk, bk, Wq, bq, Wv, bv, QT, KT, VT);
    attn_fused<<<BB*256, 256, 0, stream>>>(QT, KT, VT, x, Wo, bo, gamma, out);
}

// Round 10
// 118.905 us; speedup vs baseline: 1.2006x; 1.0067x over previous
//
#include <hip/hip_runtime.h>

// Self-attention (SAGAN-style): B=8, C=64, H=W=64 -> N=4096, E=C/8=8.
// Round 10: de-stall the attn hot loop (r9 fixed L1 aliasing; top-5 is now
// the harness's 0xAA re-poison fills, ~84us fixed -- untouchable).
// (a) K loads UNMASKED: kl is quad-independent, so all 4 quads read the same
//     256B segment (no extra L1 traffic); quads 1..3 hold real K x qf zero
//     rows = 0. Kills exec save/restore + one-time zero-init.
// (b) V row CLAMPED (lmv=min(lm,8)) instead of exec-masked: lanes 9..15
//     duplicate row 8's addresses (same lines); C rows 9..15 garbage,
//     already discarded. Row 8 stays the ones-row -> l on the MFMA pipe.
// (c) Prefetch depth 2 + #pragma unroll 2 (ping-pong regs, no rotation
//     movs): loads issue ~250 cyc ahead of use, covering L2 latency (~200).
// Kept: panelized V [b][128][16][32] (r9), in-register P via permuted key
// map (r6), raw v_exp, fused Wo/residual epilogue, LDS-free 3-pass qkv.

#define BB   8
#define CC   64
#define NPIX 4096
#define EE   8
#define BN   (BB*NPIX)        // 32768
#define YSZ  (BB*CC*NPIX)     // 2097152
#define LOG2E 1.4426950408889634f

typedef __attribute__((ext_vector_type(8))) short bf16x8;
typedef __attribute__((ext_vector_type(4))) float f32x4;

__device__ __forceinline__ unsigned short f2bf_rne(float x) {
    unsigned u = __float_as_uint(x);
    u += 0x7FFFu + ((u >> 16) & 1u);
    return (unsigned short)(u >> 16);
}
__device__ __forceinline__ unsigned pack_bf_trunc(float a, float b) {
    return (__float_as_uint(a) >> 16) | (__float_as_uint(b) & 0xFFFF0000u);
}

// ---- K1: QKV projection; V written in panel layout (unchanged from r9) ----
__global__ __launch_bounds__(256) void qkv_kernel(
    const float* __restrict__ x,
    const float* __restrict__ Wk, const float* __restrict__ bk,
    const float* __restrict__ Wq, const float* __restrict__ bq,
    const float* __restrict__ Wv, const float* __restrict__ bv,
    unsigned short* __restrict__ QT, unsigned short* __restrict__ KT,
    unsigned short* __restrict__ VT)
{
    const int proj = blockIdx.y;  // 0=Q, 1=K, 2=V
    const float* W    = (proj == 0) ? Wq : (proj == 1) ? Wk : Wv;
    const float* bias = (proj == 0) ? bq : (proj == 1) ? bk : bv;

    const int bm = blockIdx.x*256 + threadIdx.x;
    const int b  = bm >> 12;
    const int n  = bm & (NPIX-1);
    const float* xb = x + (size_t)b*CC*NPIX + n;

    float xv[CC];
    #pragma unroll
    for (int c = 0; c < CC; ++c) xv[c] = xb[(size_t)c*NPIX];

    float f[EE];
    #pragma unroll
    for (int e = 0; e < EE; ++e) {
        float acc = bias[e];
        #pragma unroll
        for (int c = 0; c < CC; ++c) acc = fmaf(W[e*CC+c], xv[c], acc);
        f[e] = acc;
    }

    if (proj == 0) {
        union { unsigned short s[8]; uint4 v; } t;
        #pragma unroll
        for (int e = 0; e < EE; ++e) t.s[e] = f2bf_rne(f[e] * LOG2E);
        *(uint4*)(QT + (size_t)bm*EE) = t.v;
    } else if (proj == 1) {
        union { unsigned short s[8]; uint4 v; } t;
        #pragma unroll
        for (int e = 0; e < EE; ++e) t.s[e] = f2bf_rne(f[e]);
        *(uint4*)(KT + (size_t)bm*EE) = t.v;
    } else {
        // panel p = n>>5; within-row short offset for key c = n&31:
        // quad q(c) block of 8: [0..3]=keys 4q..4q+3, [4..7]=keys 16+4q..+3
        const int p   = n >> 5;
        const int c   = n & 31;
        const int off = ((c & 15) >> 2)*8 + ((c >> 4) << 2) + (c & 3);
        unsigned short* vp = VT + ((size_t)(b*128 + p)*16)*32 + off;
        #pragma unroll
        for (int e = 0; e < EE; ++e) vp[e*32] = f2bf_rne(f[e]);
        vp[8*32] = 0x3F80;                         // ones row -> l via GEMM2
    }
}

// ---- K2: flash attention + fused epilogue. 16 q/block, 8 blocks/CU ----
__global__ __launch_bounds__(256, 8) void attn_fused(
    const unsigned short* __restrict__ QT, const unsigned short* __restrict__ KT,
    const unsigned short* __restrict__ VT,
    const float* __restrict__ x, const float* __restrict__ Wo,
    const float* __restrict__ bo, const float* __restrict__ gamma,
    float* __restrict__ out)
{
    __shared__ float OB[3*256];    // waves 1..3: 64 lanes x f32x4
    __shared__ float VL[16*12];    // normalized v per pixel
    __shared__ float Wos[CC*9];    // stride 9: conflict-free epilogue reads
    __shared__ float bos[CC];

    const int tid  = threadIdx.x;
    const int wave = tid >> 6, lane = tid & 63;
    const int quad = lane >> 4, lm = lane & 15;
    const int b  = blockIdx.x >> 8;
    const int m0 = (blockIdx.x & 255) * 16;

    for (int i = tid; i < CC*EE; i += 256) Wos[(i>>3)*9 + (i&7)] = Wo[i];
    if (tid < CC) bos[tid] = bo[tid];

    // B1 operand: only quad0 lanes carry real q rows; others stay zero.
    bf16x8 qf = {0,0,0,0,0,0,0,0};
    if (quad == 0)
        qf = *(const bf16x8*)(QT + (size_t)(b*NPIX + m0 + lm)*EE);

    f32x4 oacc = {0.f,0.f,0.f,0.f};
    const f32x4 zc = {0.f,0.f,0.f,0.f};

    const unsigned short* Kb = KT + (size_t)b*NPIX*EE;
    const int n_start = wave*1024;                 // split-K: 1024 keys/wave
    // K address is quad-independent: all quads read the same 256B segment.
    const unsigned short* kl = Kb + (size_t)(n_start + lm)*EE;
    // V: row clamp (rows 9..15 -> 8); same cache lines, no exec masking.
    const int lmv = (lm < 9) ? lm : 8;
    const unsigned short* vl = VT + ((size_t)(b*128 + (n_start >> 5))*16 + lmv)*32
                                  + quad*8;

    // 2-deep register pipeline: a = chunk ch, b = chunk ch+1.
    bf16x8 kf0a = *(const bf16x8*)(kl);
    bf16x8 kf1a = *(const bf16x8*)(kl + 16*EE);
    bf16x8 vfa  = *(const bf16x8*)(vl);
    bf16x8 kf0b = *(const bf16x8*)(kl + 32*EE);
    bf16x8 kf1b = *(const bf16x8*)(kl + 48*EE);
    bf16x8 vfb  = *(const bf16x8*)(vl + 512);
    kl += 64*EE; vl += 1024;

    #pragma unroll 2
    for (int ch = 0; ch < 32; ++ch) {
        bf16x8 kf0 = kf0a, kf1 = kf1a, vf = vfa;
        kf0a = kf0b; kf1a = kf1b; vfa = vfb;       // unroll-2 -> ping-pong, no movs
        if (ch < 30) {                             // prefetch chunk ch+2
            kf0b = *(const bf16x8*)(kl);
            kf1b = *(const bf16x8*)(kl + 16*EE);
            vfb  = *(const bf16x8*)(vl);
            kl += 32*EE; vl += 512;
        }

        // S: C-layout lane (quad,lm) reg r = S[key][query lm];
        // s0: key = 4*quad + r; s1: key = 16 + 4*quad + r.
        f32x4 s0 = __builtin_amdgcn_mfma_f32_16x16x32_bf16(kf0, qf, zc, 0, 0, 0);
        f32x4 s1 = __builtin_amdgcn_mfma_f32_16x16x32_bf16(kf1, qf, zc, 0, 0, 0);

        float p0 = __builtin_amdgcn_exp2f(s0.x), p1 = __builtin_amdgcn_exp2f(s0.y);
        float p2 = __builtin_amdgcn_exp2f(s0.z), p3 = __builtin_amdgcn_exp2f(s0.w);
        float p4 = __builtin_amdgcn_exp2f(s1.x), p5 = __builtin_amdgcn_exp2f(s1.y);
        float p6 = __builtin_amdgcn_exp2f(s1.z), p7 = __builtin_amdgcn_exp2f(s1.w);

        // B2 fragment IS the C-layout regs under the permuted key map
        // (slot k=quad*8+j -> key quad*4+j (j<4) / 16+quad*4+(j-4)),
        // matching the V panel row layout. Verified r6-r9.
        union { unsigned u[4]; bf16x8 v; } pu;
        pu.u[0] = pack_bf_trunc(p0, p1); pu.u[1] = pack_bf_trunc(p2, p3);
        pu.u[2] = pack_bf_trunc(p4, p5); pu.u[3] = pack_bf_trunc(p6, p7);
        oacc = __builtin_amdgcn_mfma_f32_16x16x32_bf16(vf, pu.v, oacc, 0, 0, 0);
    }

    // cross-wave combine; l rides along in C-row 8 (quad2 lanes, reg .x)
    if (wave != 0)
        *(f32x4*)(OB + (size_t)(wave-1)*256 + lane*4) = oacc;
    __syncthreads();
    if (wave == 0) {
        f32x4 o = oacc;
        #pragma unroll
        for (int w = 0; w < 3; ++w)
            o += *(f32x4*)(OB + (size_t)w*256 + lane*4);
        float l   = __shfl(o.x, 32 + lm);          // row 8 = sum of trunc(p)
        float inv = 1.f / l;
        if (quad < 2) {                            // rows e = quad*4+reg in 0..7
            f32x4 st = { o.x*inv, o.y*inv, o.z*inv, o.w*inv };
            *(f32x4*)(VL + lm*12 + quad*4) = st;
        }
    }
    __syncthreads();

    // Fused epilogue: 16 px x 64 ch over 256 threads (4 ch each).
    const float g  = gamma[0];
    const int   px = tid & 15;
    const int   cg = tid >> 4;                     // 0..15
    const size_t base = (size_t)b*CC*NPIX + (m0 + px);
    float v[EE];
    #pragma unroll
    for (int e = 0; e < EE; ++e) v[e] = VL[px*12 + e];
    #pragma unroll
    for (int i = 0; i < 4; ++i) {
        const int c = cg*4 + i;
        float o = bos[c];
        #pragma unroll
        for (int e = 0; e < EE; ++e) o += Wos[c*9 + e] * v[e];
        out[(size_t)YSZ + base + (size_t)c*NPIX] = o;
        out[base + (size_t)c*NPIX] = g*o + x[base + (size_t)c*NPIX];
    }
    if (blockIdx.x == 0 && tid == 0) out[2*(size_t)YSZ] = g;  // gamma passthrough
}

extern "C" void kernel_launch(void* const* d_in, const int* in_sizes, int n_in,
                              void* d_out, int out_size, void* d_ws, size_t ws_size,
                              hipStream_t stream) {
    const float* x     = (const float*)d_in[0];
    const float* Wk    = (const float*)d_in[1];
    const float* bk    = (const float*)d_in[2];
    const float* Wq    = (const float*)d_in[3];
    const float* bq    = (const float*)d_in[4];
    const float* Wv    = (const float*)d_in[5];
    const float* bv    = (const float*)d_in[6];
    const float* Wo    = (const float*)d_in[7];
    const float* bo    = (const float*)d_in[8];
    const float* gamma = (const float*)d_in[9];
    float* out = (float*)d_out;

    // ws: QT(512KB) | KT(512KB) | VT(1MB bf16, panelized [b][128][16][32];
    // row 8 = ones, rows 9..15 poison -> only discarded C rows) = 2MB
    unsigned short* QT = (unsigned short*)d_ws;
    unsigned short* KT = QT + (size_t)BN*EE;
    unsigned short* VT = KT + (size_t)BN*EE;

    qkv_kernel<<<dim3(BN/256, 3), 256, 0, stream>>>(x, Wk, bk, Wq, bq, Wv, bv, QT, KT, VT);
    attn_fused<<<BB*256, 256, 0, stream>>>(QT, KT, VT, x, Wo, bo, gamma, out);
}

// Round 11
// 111.119 us; speedup vs baseline: 1.2847x; 1.0701x over previous
//
#include <hip/hip_runtime.h>

// Self-attention (SAGAN-style): B=8, C=64, H=W=64 -> N=4096, E=C/8=8.
// Round 11: amortize K/V data-return. r8-r10's 16-q blocks each pull the
// whole batch K (64KB) + V panels (72KB) through L2->L1->RF; 2048 blocks =
// ~280MB return traffic whose per-CU cycles rival VALU issue -- that's the
// residual ~35us. Fix = r7's 2 query-tiles per wave (32 q/block, 1024
// blocks): same K/V loads feed 2x compute (6 MFMA + 16 exp per chunk),
// halving return traffic per query. r7 measured 46.6us even WITH the 8KB
// -stride V-thrash; with r9's panelized V that thrash is gone.
// launch_bounds(256,4): ~80 VGPRs needed, grid caps occupancy at 16
// waves/CU anyway -- don't force a 64-reg spill. pack via v_perm_b32
// (__builtin_amdgcn_perm, 1 instr). Kept: panel V [b][128][16][32] with
// ones-row 8 (l = sum(p) on the MFMA pipe), in-register P via permuted key
// map (verified r6-r10), raw v_exp, depth-2 register prefetch, fused
// Wo/residual epilogue, LDS-free 3-pass qkv.
// Non-attn ~84us is fixed harness overhead (0xAA re-poison fills at 78% of
// HBM peak + restores); attn is the only lever.

#define BB   8
#define CC   64
#define NPIX 4096
#define EE   8
#define BN   (BB*NPIX)        // 32768
#define YSZ  (BB*CC*NPIX)     // 2097152
#define LOG2E 1.4426950408889634f

typedef __attribute__((ext_vector_type(8))) short bf16x8;
typedef __attribute__((ext_vector_type(4))) float f32x4;

__device__ __forceinline__ unsigned short f2bf_rne(float x) {
    unsigned u = __float_as_uint(x);
    u += 0x7FFFu + ((u >> 16) & 1u);
    return (unsigned short)(u >> 16);
}
// dst = [hi16(a), hi16(b)] in one v_perm_b32 (truncation; bias cancels in
// the softmax normalize since l sums the same truncated p via the ones-row).
__device__ __forceinline__ unsigned pack_bf_trunc(float a, float b) {
    return __builtin_amdgcn_perm(__float_as_uint(b), __float_as_uint(a),
                                 0x07060302u);
}

// ---- K1: QKV projection; V written in panel layout (unchanged from r9) ----
__global__ __launch_bounds__(256) void qkv_kernel(
    const float* __restrict__ x,
    const float* __restrict__ Wk, const float* __restrict__ bk,
    const float* __restrict__ Wq, const float* __restrict__ bq,
    const float* __restrict__ Wv, const float* __restrict__ bv,
    unsigned short* __restrict__ QT, unsigned short* __restrict__ KT,
    unsigned short* __restrict__ VT)
{
    const int proj = blockIdx.y;  // 0=Q, 1=K, 2=V
    const float* W    = (proj == 0) ? Wq : (proj == 1) ? Wk : Wv;
    const float* bias = (proj == 0) ? bq : (proj == 1) ? bk : bv;

    const int bm = blockIdx.x*256 + threadIdx.x;
    const int b  = bm >> 12;
    const int n  = bm & (NPIX-1);
    const float* xb = x + (size_t)b*CC*NPIX + n;

    float xv[CC];
    #pragma unroll
    for (int c = 0; c < CC; ++c) xv[c] = xb[(size_t)c*NPIX];

    float f[EE];
    #pragma unroll
    for (int e = 0; e < EE; ++e) {
        float acc = bias[e];
        #pragma unroll
        for (int c = 0; c < CC; ++c) acc = fmaf(W[e*CC+c], xv[c], acc);
        f[e] = acc;
    }

    if (proj == 0) {
        union { unsigned short s[8]; uint4 v; } t;
        #pragma unroll
        for (int e = 0; e < EE; ++e) t.s[e] = f2bf_rne(f[e] * LOG2E);
        *(uint4*)(QT + (size_t)bm*EE) = t.v;
    } else if (proj == 1) {
        union { unsigned short s[8]; uint4 v; } t;
        #pragma unroll
        for (int e = 0; e < EE; ++e) t.s[e] = f2bf_rne(f[e]);
        *(uint4*)(KT + (size_t)bm*EE) = t.v;
    } else {
        // panel p = n>>5; within-row short offset for key c = n&31:
        // quad q(c) block of 8: [0..3]=keys 4q..4q+3, [4..7]=keys 16+4q..+3
        const int p   = n >> 5;
        const int c   = n & 31;
        const int off = ((c & 15) >> 2)*8 + ((c >> 4) << 2) + (c & 3);
        unsigned short* vp = VT + ((size_t)(b*128 + p)*16)*32 + off;
        #pragma unroll
        for (int e = 0; e < EE; ++e) vp[e*32] = f2bf_rne(f[e]);
        vp[8*32] = 0x3F80;                         // ones row -> l via GEMM2
    }
}

// ---- K2: flash attention, 2 q-tiles/wave + fused epilogue ----
// Block = 32 queries; 4 waves split the 4096 keys x4. Grid = 8*128 = 1024.
__global__ __launch_bounds__(256, 4) void attn_fused(
    const unsigned short* __restrict__ QT, const unsigned short* __restrict__ KT,
    const unsigned short* __restrict__ VT,
    const float* __restrict__ x, const float* __restrict__ Wo,
    const float* __restrict__ bo, const float* __restrict__ gamma,
    float* __restrict__ out)
{
    __shared__ float OB[3*2*256];  // waves 1..3 x {A,B} x 64 lanes x f32x4
    __shared__ float VL[32*12];    // normalized v per pixel
    __shared__ float Wos[CC*9];    // stride 9: conflict-free epilogue reads
    __shared__ float bos[CC];

    const int tid  = threadIdx.x;
    const int wave = tid >> 6, lane = tid & 63;
    const int quad = lane >> 4, lm = lane & 15;
    const int b  = blockIdx.x >> 7;
    const int m0 = (blockIdx.x & 127) * 32;

    for (int i = tid; i < CC*EE; i += 256) Wos[(i>>3)*9 + (i&7)] = Wo[i];
    if (tid < CC) bos[tid] = bo[tid];

    // B1 operands: only quad0 lanes carry real q rows; others stay zero.
    bf16x8 qfA = {0,0,0,0,0,0,0,0}, qfB = {0,0,0,0,0,0,0,0};
    if (quad == 0) {
        qfA = *(const bf16x8*)(QT + (size_t)(b*NPIX + m0 + lm)*EE);
        qfB = *(const bf16x8*)(QT + (size_t)(b*NPIX + m0 + 16 + lm)*EE);
    }

    f32x4 oaccA = {0.f,0.f,0.f,0.f}, oaccB = {0.f,0.f,0.f,0.f};
    const f32x4 zc = {0.f,0.f,0.f,0.f};

    const unsigned short* Kb = KT + (size_t)b*NPIX*EE;
    const int n_start = wave*1024;                 // split-K: 1024 keys/wave
    // K address is quad-independent: all quads hit the same 256B segment;
    // quads 1..3 hold real K x qf zero rows = 0 contribution.
    const unsigned short* kl = Kb + (size_t)(n_start + lm)*EE;
    // V panel: row clamp (rows 9..15 -> 8; same lines, C rows 9..15 discarded)
    const int lmv = (lm < 9) ? lm : 8;
    const unsigned short* vl = VT + ((size_t)(b*128 + (n_start >> 5))*16 + lmv)*32
                                  + quad*8;

    // 2-deep register pipeline
    bf16x8 kf0a = *(const bf16x8*)(kl);
    bf16x8 kf1a = *(const bf16x8*)(kl + 16*EE);
    bf16x8 vfa  = *(const bf16x8*)(vl);
    bf16x8 kf0b = *(const bf16x8*)(kl + 32*EE);
    bf16x8 kf1b = *(const bf16x8*)(kl + 48*EE);
    bf16x8 vfb  = *(const bf16x8*)(vl + 512);
    kl += 64*EE; vl += 1024;

    #pragma unroll 2
    for (int ch = 0; ch < 32; ++ch) {
        bf16x8 kf0 = kf0a, kf1 = kf1a, vf = vfa;
        kf0a = kf0b; kf1a = kf1b; vfa = vfb;       // ping-pong, no movs
        if (ch < 30) {                             // prefetch chunk ch+2
            kf0b = *(const bf16x8*)(kl);
            kf1b = *(const bf16x8*)(kl + 16*EE);
            vfb  = *(const bf16x8*)(vl);
            kl += 32*EE; vl += 512;
        }

        // S: C-layout lane (quad,lm) reg r = S[key][query];
        // s0: key = 4*quad + r; s1: key = 16 + 4*quad + r.
        f32x4 s0a = __builtin_amdgcn_mfma_f32_16x16x32_bf16(kf0, qfA, zc, 0, 0, 0);
        f32x4 s1a = __builtin_amdgcn_mfma_f32_16x16x32_bf16(kf1, qfA, zc, 0, 0, 0);
        f32x4 s0b = __builtin_amdgcn_mfma_f32_16x16x32_bf16(kf0, qfB, zc, 0, 0, 0);
        f32x4 s1b = __builtin_amdgcn_mfma_f32_16x16x32_bf16(kf1, qfB, zc, 0, 0, 0);

        float a0 = __builtin_amdgcn_exp2f(s0a.x), a1 = __builtin_amdgcn_exp2f(s0a.y);
        float a2 = __builtin_amdgcn_exp2f(s0a.z), a3 = __builtin_amdgcn_exp2f(s0a.w);
        float a4 = __builtin_amdgcn_exp2f(s1a.x), a5 = __builtin_amdgcn_exp2f(s1a.y);
        float a6 = __builtin_amdgcn_exp2f(s1a.z), a7 = __builtin_amdgcn_exp2f(s1a.w);
        float b0 = __builtin_amdgcn_exp2f(s0b.x), b1 = __builtin_amdgcn_exp2f(s0b.y);
        float b2 = __builtin_amdgcn_exp2f(s0b.z), b3 = __builtin_amdgcn_exp2f(s0b.w);
        float b4 = __builtin_amdgcn_exp2f(s1b.x), b5 = __builtin_amdgcn_exp2f(s1b.y);
        float b6 = __builtin_amdgcn_exp2f(s1b.z), b7 = __builtin_amdgcn_exp2f(s1b.w);

        // B2 fragment IS the C-layout regs under the permuted key map
        // (slot k=quad*8+j -> key quad*4+j (j<4) / 16+quad*4+(j-4)),
        // matching the V panel row layout. Verified r6-r10.
        union { unsigned u[4]; bf16x8 v; } puA, puB;
        puA.u[0] = pack_bf_trunc(a0, a1); puA.u[1] = pack_bf_trunc(a2, a3);
        puA.u[2] = pack_bf_trunc(a4, a5); puA.u[3] = pack_bf_trunc(a6, a7);
        puB.u[0] = pack_bf_trunc(b0, b1); puB.u[1] = pack_bf_trunc(b2, b3);
        puB.u[2] = pack_bf_trunc(b4, b5); puB.u[3] = pack_bf_trunc(b6, b7);
        oaccA = __builtin_amdgcn_mfma_f32_16x16x32_bf16(vf, puA.v, oaccA, 0, 0, 0);
        oaccB = __builtin_amdgcn_mfma_f32_16x16x32_bf16(vf, puB.v, oaccB, 0, 0, 0);
    }

    // cross-wave combine; l rides along in C-row 8 (quad2 lanes, reg .x)
    if (wave != 0) {
        *(f32x4*)(OB + ((size_t)(wave-1)*2 + 0)*256 + lane*4) = oaccA;
        *(f32x4*)(OB + ((size_t)(wave-1)*2 + 1)*256 + lane*4) = oaccB;
    }
    __syncthreads();
    if (wave == 0) {
        f32x4 oA = oaccA, oB = oaccB;
        #pragma unroll
        for (int w = 0; w < 3; ++w) {
            oA += *(f32x4*)(OB + ((size_t)w*2 + 0)*256 + lane*4);
            oB += *(f32x4*)(OB + ((size_t)w*2 + 1)*256 + lane*4);
        }
        float lA = __shfl(oA.x, 32 + lm);          // row 8 = sum of trunc(p)
        float lB = __shfl(oB.x, 32 + lm);
        float invA = 1.f / lA, invB = 1.f / lB;
        if (quad < 2) {                            // rows e = quad*4+reg in 0..7
            f32x4 sA = { oA.x*invA, oA.y*invA, oA.z*invA, oA.w*invA };
            f32x4 sB = { oB.x*invB, oB.y*invB, oB.z*invB, oB.w*invB };
            *(f32x4*)(VL + lm*12 + quad*4)        = sA;
            *(f32x4*)(VL + (16 + lm)*12 + quad*4) = sB;
        }
    }
    __syncthreads();

    // Fused epilogue: 32 px x 64 ch over 256 threads (8 ch each).
    const float g  = gamma[0];
    const int   px = tid & 31;
    const int   cg = tid >> 5;                     // 0..7
    const size_t base = (size_t)b*CC*NPIX + (m0 + px);
    float v[EE];
    #pragma unroll
    for (int e = 0; e < EE; ++e) v[e] = VL[px*12 + e];
    #pragma unroll
    for (int i = 0; i < 8; ++i) {
        const int c = cg*8 + i;
        float o = bos[c];
        #pragma unroll
        for (int e = 0; e < EE; ++e) o += Wos[c*9 + e] * v[e];
        out[(size_t)YSZ + base + (size_t)c*NPIX] = o;
        out[base + (size_t)c*NPIX] = g*o + x[base + (size_t)c*NPIX];
    }
    if (blockIdx.x == 0 && tid == 0) out[2*(size_t)YSZ] = g;  // gamma passthrough
}

extern "C" void kernel_launch(void* const* d_in, const int* in_sizes, int n_in,
                              void* d_out, int out_size, void* d_ws, size_t ws_size,
                              hipStream_t stream) {
    const float* x     = (const float*)d_in[0];
    const float* Wk    = (const float*)d_in[1];
    const float* bk    = (const float*)d_in[2];
    const float* Wq    = (const float*)d_in[3];
    const float* bq    = (const float*)d_in[4];
    const float* Wv    = (const float*)d_in[5];
    const float* bv    = (const float*)d_in[6];
    const float* Wo    = (const float*)d_in[7];
    const float* bo    = (const float*)d_in[8];
    const float* gamma = (const float*)d_in[9];
    float* out = (float*)d_out;

    // ws: QT(512KB) | KT(512KB) | VT(1MB bf16, panelized [b][128][16][32];
    // row 8 = ones, rows 9..15 poison -> only discarded C rows) = 2MB
    unsigned short* QT = (unsigned short*)d_ws;
    unsigned short* KT = QT + (size_t)BN*EE;
    unsigned short* VT = KT + (size_t)BN*EE;

    qkv_kernel<<<dim3(BN/256, 3), 256, 0, stream>>>(x, Wk, bk, Wq, bq, Wv, bv, QT, KT, VT);
    attn_fused<<<BB*128, 256, 0, stream>>>(QT, KT, VT, x, Wo, bo, gamma, out);
}